// Round 1
// baseline (212.552 us; speedup 1.0000x reference)
//
#include <hip/hip_runtime.h>

#define BLOCK 256

// One block per graph. graph_indices is SORTED, so each graph owns a
// contiguous node range [s, e) found by binary search.
//
// value:  sigmoid(segsum(VE)@W + b) == sigmoid(segsum(VE@W) + b)
//         == sigmoid( sum over flat range of ve_flat[j]*W[j&63] + b )
//         -> coalesced float4 stream; W fragment is loop-invariant per thread.
// log_pi: 3 local passes over the graph's ~4KB pi slice (L1-resident after
//         first pass): max, sum-exp, write (pi - lse).
__global__ __launch_bounds__(BLOCK) void pv_fused(
    const float* __restrict__ pi,
    const float* __restrict__ ve,
    const float* __restrict__ W,
    const float* __restrict__ bias,
    const int*   __restrict__ idx32,
    float*       __restrict__ out,   // [N] log_pi, then [G] value
    int N, int G)
{
    const int g    = (int)blockIdx.x;
    const int t    = (int)threadIdx.x;
    const int lane = t & 63;
    const int wid  = t >> 6;

    __shared__ int   sB[2];
    __shared__ float red[BLOCK / 64];
    __shared__ float bc;

    if (t < 2) {
        // int64 vs int32 index detection: for little-endian int64 values
        // (< 2^31, nonneg), the final 32-bit word is a high half == 0.
        // For int32, idx32[N-1] is the largest (sorted) index, > 0.
        const int stride = (idx32[N - 1] == 0) ? 2 : 1;
        const int val = g + t;
        int lo = 0, hi = N;
        while (lo < hi) {
            const int mid = (lo + hi) >> 1;
            if (idx32[(size_t)mid * (size_t)stride] < val) lo = mid + 1;
            else hi = mid;
        }
        sB[t] = lo;
    }
    __syncthreads();
    const int s = sB[0];
    const int e = sB[1];

    // ---------------- value head: segment dot-sum ----------------
    float4 w4;
    {
        const int k4 = (t & 15) << 2;   // f0 = s*16 + t, stride 256 => f&15 == t&15 invariant
        w4.x = W[k4 + 0]; w4.y = W[k4 + 1]; w4.z = W[k4 + 2]; w4.w = W[k4 + 3];
    }
    float acc = 0.f;
    {
        const float4* __restrict__ ve4 = (const float4*)ve;
        const long long f0 = (long long)s * 16;
        const long long f1 = (long long)e * 16;
        for (long long f = f0 + t; f < f1; f += BLOCK) {
            const float4 v = ve4[f];
            acc = fmaf(v.x, w4.x, acc);
            acc = fmaf(v.y, w4.y, acc);
            acc = fmaf(v.z, w4.z, acc);
            acc = fmaf(v.w, w4.w, acc);
        }
    }
    #pragma unroll
    for (int o = 32; o > 0; o >>= 1) acc += __shfl_down(acc, o, 64);
    if (lane == 0) red[wid] = acc;
    __syncthreads();
    if (t == 0) {
        const float v = red[0] + red[1] + red[2] + red[3];
        out[(size_t)N + (size_t)g] = 1.f / (1.f + __expf(-(v + bias[0])));
    }
    __syncthreads();

    // ---------------- segment log-softmax of pi ----------------
    float m = -INFINITY;
    for (int n = s + t; n < e; n += BLOCK) m = fmaxf(m, pi[n]);
    #pragma unroll
    for (int o = 32; o > 0; o >>= 1) m = fmaxf(m, __shfl_down(m, o, 64));
    if (lane == 0) red[wid] = m;
    __syncthreads();
    if (t == 0) bc = fmaxf(fmaxf(red[0], red[1]), fmaxf(red[2], red[3]));
    __syncthreads();
    m = bc;

    float se = 0.f;
    for (int n = s + t; n < e; n += BLOCK) se += __expf(pi[n] - m);
    #pragma unroll
    for (int o = 32; o > 0; o >>= 1) se += __shfl_down(se, o, 64);
    if (lane == 0) red[wid] = se;
    __syncthreads();
    if (t == 0) bc = m + __logf(red[0] + red[1] + red[2] + red[3]);
    __syncthreads();
    const float lse = bc;

    for (int n = s + t; n < e; n += BLOCK) out[n] = pi[n] - lse;
}

extern "C" void kernel_launch(void* const* d_in, const int* in_sizes, int n_in,
                              void* d_out, int out_size, void* d_ws, size_t ws_size,
                              hipStream_t stream) {
    const float* pi  = (const float*)d_in[0];
    const float* ve  = (const float*)d_in[1];
    const float* W   = (const float*)d_in[2];
    const float* b   = (const float*)d_in[3];
    const int*   idx = (const int*)d_in[4];
    float* out = (float*)d_out;

    const int N = in_sizes[0];           // pi is [N,1]
    const int G = out_size - N;          // outputs: [N] log_pi + [G] value

    pv_fused<<<G, BLOCK, 0, stream>>>(pi, ve, W, b, idx, out, N, G);
}

// Round 3
// 188.536 us; speedup vs baseline: 1.1274x; 1.1274x over previous
//
#include <hip/hip_runtime.h>

#define BLOCK 256

typedef float f4 __attribute__((ext_vector_type(4)));  // native vector: OK for nontemporal builtins

// One block per graph (indices sorted -> contiguous [s,e) range per graph,
// found by binary search). value = sigmoid(segsum(VE@W)+b) computed as a
// flat coalesced float4 stream (W fragment loop-invariant per thread since
// stride 256 float4s == 0 mod 16). log_pi via 3 local passes over the
// graph's ~4KB pi slice (L1-resident after first pass).
__global__ __launch_bounds__(BLOCK) void pv_fused(
    const float* __restrict__ pi,
    const float* __restrict__ ve,
    const float* __restrict__ W,
    const float* __restrict__ bias,
    const int*   __restrict__ idx32,
    float*       __restrict__ out,   // [N] log_pi, then [G] value
    int N, int G)
{
    const int g    = (int)blockIdx.x;
    const int t    = (int)threadIdx.x;
    const int lane = t & 63;
    const int wid  = t >> 6;

    __shared__ int   sB[2];
    __shared__ float red[BLOCK / 64];
    __shared__ float bc;

    if (t < 2) {
        // int64 vs int32 layout detection: for sorted nonneg int64, the last
        // 32-bit word is a high half == 0; for int32 it's the max index > 0.
        const int stride = (idx32[N - 1] == 0) ? 2 : 1;
        const int val = g + t;
        int lo = 0, hi = N;
        while (lo < hi) {
            const int mid = (lo + hi) >> 1;
            if (idx32[(size_t)mid * (size_t)stride] < val) lo = mid + 1;
            else hi = mid;
        }
        sB[t] = lo;
    }
    __syncthreads();
    const int s = sB[0];
    const int e = sB[1];

    // ---------------- value head: segment dot-sum over ve stream ----------------
    f4 w4;
    {
        const int k4 = (t & 15) << 2;   // f = s*16 + t + k*256 => f&15 == t&15
        w4.x = W[k4 + 0]; w4.y = W[k4 + 1]; w4.z = W[k4 + 2]; w4.w = W[k4 + 3];
    }
    float a0 = 0.f, a1 = 0.f, a2 = 0.f, a3 = 0.f;
    {
        const f4* __restrict__ ve4 = (const f4*)ve;
        const int f1 = e * 16;          // N*16 = 67M < 2^31: int32 safe
        int f = s * 16 + t;
        // 4-deep unroll: 4 independent nontemporal loads in flight
        for (; f + 3 * BLOCK < f1; f += 4 * BLOCK) {
            const f4 v0 = __builtin_nontemporal_load(&ve4[f]);
            const f4 v1 = __builtin_nontemporal_load(&ve4[f + BLOCK]);
            const f4 v2 = __builtin_nontemporal_load(&ve4[f + 2 * BLOCK]);
            const f4 v3 = __builtin_nontemporal_load(&ve4[f + 3 * BLOCK]);
            a0 = fmaf(v0.x, w4.x, a0); a0 = fmaf(v0.y, w4.y, a0);
            a0 = fmaf(v0.z, w4.z, a0); a0 = fmaf(v0.w, w4.w, a0);
            a1 = fmaf(v1.x, w4.x, a1); a1 = fmaf(v1.y, w4.y, a1);
            a1 = fmaf(v1.z, w4.z, a1); a1 = fmaf(v1.w, w4.w, a1);
            a2 = fmaf(v2.x, w4.x, a2); a2 = fmaf(v2.y, w4.y, a2);
            a2 = fmaf(v2.z, w4.z, a2); a2 = fmaf(v2.w, w4.w, a2);
            a3 = fmaf(v3.x, w4.x, a3); a3 = fmaf(v3.y, w4.y, a3);
            a3 = fmaf(v3.z, w4.z, a3); a3 = fmaf(v3.w, w4.w, a3);
        }
        for (; f < f1; f += BLOCK) {
            const f4 v = __builtin_nontemporal_load(&ve4[f]);
            a0 = fmaf(v.x, w4.x, a0); a0 = fmaf(v.y, w4.y, a0);
            a0 = fmaf(v.z, w4.z, a0); a0 = fmaf(v.w, w4.w, a0);
        }
    }
    float acc = (a0 + a1) + (a2 + a3);
    #pragma unroll
    for (int o = 32; o > 0; o >>= 1) acc += __shfl_down(acc, o, 64);
    if (lane == 0) red[wid] = acc;
    __syncthreads();
    if (t == 0) {
        const float v = red[0] + red[1] + red[2] + red[3];
        out[(size_t)N + (size_t)g] = 1.f / (1.f + __expf(-(v + bias[0])));
    }
    __syncthreads();

    // ---------------- segment log-softmax of pi ----------------
    float m = -INFINITY;
    for (int n = s + t; n < e; n += BLOCK) m = fmaxf(m, pi[n]);
    #pragma unroll
    for (int o = 32; o > 0; o >>= 1) m = fmaxf(m, __shfl_down(m, o, 64));
    if (lane == 0) red[wid] = m;
    __syncthreads();
    if (t == 0) bc = fmaxf(fmaxf(red[0], red[1]), fmaxf(red[2], red[3]));
    __syncthreads();
    m = bc;

    float se = 0.f;
    for (int n = s + t; n < e; n += BLOCK) se += __expf(pi[n] - m);
    #pragma unroll
    for (int o = 32; o > 0; o >>= 1) se += __shfl_down(se, o, 64);
    if (lane == 0) red[wid] = se;
    __syncthreads();
    if (t == 0) bc = m + __logf(red[0] + red[1] + red[2] + red[3]);
    __syncthreads();
    const float lse = bc;

    for (int n = s + t; n < e; n += BLOCK) out[n] = pi[n] - lse;
}

extern "C" void kernel_launch(void* const* d_in, const int* in_sizes, int n_in,
                              void* d_out, int out_size, void* d_ws, size_t ws_size,
                              hipStream_t stream) {
    const float* pi  = (const float*)d_in[0];
    const float* ve  = (const float*)d_in[1];
    const float* W   = (const float*)d_in[2];
    const float* b   = (const float*)d_in[3];
    const int*   idx = (const int*)d_in[4];
    float* out = (float*)d_out;

    const int N = in_sizes[0];           // pi is [N,1]
    const int G = out_size - N;          // outputs: [N] log_pi + [G] value

    pv_fused<<<G, BLOCK, 0, stream>>>(pi, ve, W, b, idx, out, N, G);
}

// Round 4
// 183.412 us; speedup vs baseline: 1.1589x; 1.0279x over previous
//
#include <hip/hip_runtime.h>

#define BLOCK 256

typedef float f4 __attribute__((ext_vector_type(4)));  // native vector: OK for nontemporal builtins

// One block per graph (indices sorted -> contiguous [s,e) range).
// Boundaries found by wave-cooperative 64-ary search (4 rounds of
// ballot+popcount instead of 22 serial dependent HBM misses).
// value = sigmoid(segsum(VE@W)+b) computed as a flat coalesced float4
// nontemporal stream (W fragment loop-invariant per thread since stride 256
// float4s == 0 mod 16). log_pi via 3 local passes over the graph's ~4KB pi
// slice (L1-resident after first pass).
__global__ __launch_bounds__(BLOCK) void pv_fused(
    const float* __restrict__ pi,
    const float* __restrict__ ve,
    const float* __restrict__ W,
    const float* __restrict__ bias,
    const int*   __restrict__ idx32,
    float*       __restrict__ out,   // [N] log_pi, then [G] value
    int N, int G)
{
    const int g    = (int)blockIdx.x;
    const int t    = (int)threadIdx.x;
    const int lane = t & 63;
    const int wid  = t >> 6;

    __shared__ int   sB[2];
    __shared__ float red[BLOCK / 64];
    __shared__ float bc;

    // ---- wave-cooperative 64-ary boundary search: wave0 -> s, wave1 -> e ----
    if (wid < 2) {
        // int64 vs int32 layout detection: for sorted nonneg int64, the last
        // 32-bit word is a high half == 0; for int32 it's the max index > 0.
        const int stride = (idx32[N - 1] == 0) ? 2 : 1;
        const int v = g + wid;
        int lo = 0, hi = N;   // invariant: idx[<lo] < v, idx[>=hi] >= v
        while (hi > lo) {
            const int len  = hi - lo;
            const int step = (len + 63) >> 6;          // ceil(len/64)
            const int q    = lo + lane * step;
            bool pred = false;
            if (q < hi) pred = (idx32[q * stride] < v);
            const unsigned long long mask = __ballot(pred);
            const int k = __popcll(mask);              // monotone: probes 0..k-1 true
            const int nlo = (k > 0) ? (lo + (k - 1) * step + 1) : lo;
            int nhi = (k < 64) ? (lo + k * step) : hi;
            if (nhi > hi) nhi = hi;
            lo = nlo; hi = nhi;
        }
        if (lane == 0) sB[wid] = lo;
    }
    __syncthreads();
    const int s = sB[0];
    const int e = sB[1];

    // ---------------- value head: segment dot-sum over ve stream ----------------
    f4 w4;
    {
        const int k4 = (t & 15) << 2;   // f = s*16 + t + k*256 => f&15 == t&15
        w4.x = W[k4 + 0]; w4.y = W[k4 + 1]; w4.z = W[k4 + 2]; w4.w = W[k4 + 3];
    }
    float a0 = 0.f, a1 = 0.f, a2 = 0.f, a3 = 0.f;
    {
        const f4* __restrict__ ve4 = (const f4*)ve;
        const int f1 = e * 16;          // N*16 = 67M < 2^31: int32 safe
        int f = s * 16 + t;
        // 4-deep unroll: 4 independent nontemporal loads in flight
        for (; f + 3 * BLOCK < f1; f += 4 * BLOCK) {
            const f4 v0 = __builtin_nontemporal_load(&ve4[f]);
            const f4 v1 = __builtin_nontemporal_load(&ve4[f + BLOCK]);
            const f4 v2 = __builtin_nontemporal_load(&ve4[f + 2 * BLOCK]);
            const f4 v3 = __builtin_nontemporal_load(&ve4[f + 3 * BLOCK]);
            a0 = fmaf(v0.x, w4.x, a0); a0 = fmaf(v0.y, w4.y, a0);
            a0 = fmaf(v0.z, w4.z, a0); a0 = fmaf(v0.w, w4.w, a0);
            a1 = fmaf(v1.x, w4.x, a1); a1 = fmaf(v1.y, w4.y, a1);
            a1 = fmaf(v1.z, w4.z, a1); a1 = fmaf(v1.w, w4.w, a1);
            a2 = fmaf(v2.x, w4.x, a2); a2 = fmaf(v2.y, w4.y, a2);
            a2 = fmaf(v2.z, w4.z, a2); a2 = fmaf(v2.w, w4.w, a2);
            a3 = fmaf(v3.x, w4.x, a3); a3 = fmaf(v3.y, w4.y, a3);
            a3 = fmaf(v3.z, w4.z, a3); a3 = fmaf(v3.w, w4.w, a3);
        }
        for (; f < f1; f += BLOCK) {
            const f4 v = __builtin_nontemporal_load(&ve4[f]);
            a0 = fmaf(v.x, w4.x, a0); a0 = fmaf(v.y, w4.y, a0);
            a0 = fmaf(v.z, w4.z, a0); a0 = fmaf(v.w, w4.w, a0);
        }
    }
    float acc = (a0 + a1) + (a2 + a3);
    #pragma unroll
    for (int o = 32; o > 0; o >>= 1) acc += __shfl_down(acc, o, 64);
    if (lane == 0) red[wid] = acc;
    __syncthreads();
    if (t == 0) {
        const float v = red[0] + red[1] + red[2] + red[3];
        out[(size_t)N + (size_t)g] = 1.f / (1.f + __expf(-(v + bias[0])));
    }
    __syncthreads();

    // ---------------- segment log-softmax of pi ----------------
    float m = -INFINITY;
    for (int n = s + t; n < e; n += BLOCK) m = fmaxf(m, pi[n]);
    #pragma unroll
    for (int o = 32; o > 0; o >>= 1) m = fmaxf(m, __shfl_down(m, o, 64));
    if (lane == 0) red[wid] = m;
    __syncthreads();
    if (t == 0) bc = fmaxf(fmaxf(red[0], red[1]), fmaxf(red[2], red[3]));
    __syncthreads();
    m = bc;

    float se = 0.f;
    for (int n = s + t; n < e; n += BLOCK) se += __expf(pi[n] - m);
    #pragma unroll
    for (int o = 32; o > 0; o >>= 1) se += __shfl_down(se, o, 64);
    if (lane == 0) red[wid] = se;
    __syncthreads();
    if (t == 0) bc = m + __logf(red[0] + red[1] + red[2] + red[3]);
    __syncthreads();
    const float lse = bc;

    for (int n = s + t; n < e; n += BLOCK)
        __builtin_nontemporal_store(pi[n] - lse, &out[n]);
}

extern "C" void kernel_launch(void* const* d_in, const int* in_sizes, int n_in,
                              void* d_out, int out_size, void* d_ws, size_t ws_size,
                              hipStream_t stream) {
    const float* pi  = (const float*)d_in[0];
    const float* ve  = (const float*)d_in[1];
    const float* W   = (const float*)d_in[2];
    const float* b   = (const float*)d_in[3];
    const int*   idx = (const int*)d_in[4];
    float* out = (float*)d_out;

    const int N = in_sizes[0];           // pi is [N,1]
    const int G = out_size - N;          // outputs: [N] log_pi + [G] value

    pv_fused<<<G, BLOCK, 0, stream>>>(pi, ve, W, b, idx, out, N, G);
}